// Round 2
// baseline (689.088 us; speedup 1.0000x reference)
//
#include <hip/hip_runtime.h>
#include <hip/hip_bf16.h>

// SplineConv, K=2 degree-1 B-spline, 1-D pseudo-coords.
// out[n] = relu( mean_{e->n}( (1-v)x_src@W0 + v x_src@W1 ) + x[n]@root + bias )
// Refactored: S[n]=sum x_src, A1[n]=sum v*x_src  (scatter w/ atomics),
// then out = relu( (S*inv)@W0 + (A1*inv)@(W1-W0) + x@root + bias ) as one
// fused K=192 GEMM with combined weight M[192][64] in LDS.

#define CH 64

__global__ __launch_bounds__(256) void spline_scatter(
    const float* __restrict__ x, const int* __restrict__ ei,
    const float* __restrict__ attr, float* __restrict__ S,
    float* __restrict__ A1, float* __restrict__ deg, int E) {
  int w = (int)((blockIdx.x * 4) + (threadIdx.x >> 6));  // one wave per edge
  int lane = threadIdx.x & 63;
  if (w >= E) return;
  int src = ei[w];
  int dst = ei[E + w];
  float v = attr[w];  // K=2: frac = v, basis = [1-v, v]
  float xv = x[(size_t)src * CH + lane];
  atomicAdd(&S[(size_t)dst * CH + lane], xv);
  atomicAdd(&A1[(size_t)dst * CH + lane], v * xv);
  if (lane == 0) atomicAdd(&deg[dst], 1.0f);
}

__device__ __forceinline__ void accum_seg(float acc[CH], const float4* __restrict__ in4,
                                          float scale, const float* __restrict__ Mbase) {
#pragma unroll 4
  for (int i4 = 0; i4 < 16; ++i4) {
    float4 sv = in4[i4];
    float vals[4];
    vals[0] = sv.x * scale; vals[1] = sv.y * scale;
    vals[2] = sv.z * scale; vals[3] = sv.w * scale;
#pragma unroll
    for (int j = 0; j < 4; ++j) {
      const float4* Mr = (const float4*)(Mbase + (i4 * 4 + j) * CH);
      float s = vals[j];
#pragma unroll
      for (int o4 = 0; o4 < 16; ++o4) {
        float4 m = Mr[o4];
        acc[o4 * 4 + 0] = fmaf(s, m.x, acc[o4 * 4 + 0]);
        acc[o4 * 4 + 1] = fmaf(s, m.y, acc[o4 * 4 + 1]);
        acc[o4 * 4 + 2] = fmaf(s, m.z, acc[o4 * 4 + 2]);
        acc[o4 * 4 + 3] = fmaf(s, m.w, acc[o4 * 4 + 3]);
      }
    }
  }
}

__global__ __launch_bounds__(256) void spline_gemm(
    const float* __restrict__ S, const float* __restrict__ A1,
    const float* __restrict__ deg, const float* __restrict__ x,
    const float* __restrict__ W, const float* __restrict__ root,
    const float* __restrict__ bias, float* __restrict__ out, int n) {
  __shared__ float M[192 * CH];   // rows 0..63: W0; 64..127: W1-W0; 128..191: root
  __shared__ float bs[CH];
  int t = threadIdx.x;
  for (int idx = t; idx < 64 * 64; idx += 256) {
    int i = idx >> 6, o = idx & 63;
    float w0 = W[i * 64 + o];
    float w1 = W[4096 + i * 64 + o];
    M[i * 64 + o] = w0;
    M[(64 + i) * 64 + o] = w1 - w0;
    M[(128 + i) * 64 + o] = root[i * 64 + o];
  }
  if (t < 64) bs[t] = bias[t];
  __syncthreads();

  int node = blockIdx.x * 256 + t;
  if (node >= n) return;

  float acc[CH];
#pragma unroll
  for (int o = 0; o < CH; ++o) acc[o] = 0.0f;

  float inv = 1.0f / fmaxf(deg[node], 1.0f);
  const float4* S4 = (const float4*)(S + (size_t)node * CH);
  const float4* A4 = (const float4*)(A1 + (size_t)node * CH);
  const float4* X4 = (const float4*)(x + (size_t)node * CH);

  accum_seg(acc, S4, inv, M);            // (S*inv) @ W0
  accum_seg(acc, A4, inv, M + 64 * CH);  // (A1*inv) @ (W1-W0)
  accum_seg(acc, X4, 1.0f, M + 128 * CH);// x @ root

  float4* O4 = (float4*)(out + (size_t)node * CH);
#pragma unroll
  for (int o4 = 0; o4 < 16; ++o4) {
    float4 r;
    r.x = fmaxf(acc[o4 * 4 + 0] + bs[o4 * 4 + 0], 0.0f);
    r.y = fmaxf(acc[o4 * 4 + 1] + bs[o4 * 4 + 1], 0.0f);
    r.z = fmaxf(acc[o4 * 4 + 2] + bs[o4 * 4 + 2], 0.0f);
    r.w = fmaxf(acc[o4 * 4 + 3] + bs[o4 * 4 + 3], 0.0f);
    O4[o4] = r;
  }
}

extern "C" void kernel_launch(void* const* d_in, const int* in_sizes, int n_in,
                              void* d_out, int out_size, void* d_ws, size_t ws_size,
                              hipStream_t stream) {
  const float* x    = (const float*)d_in[0];
  const int*   ei   = (const int*)d_in[1];
  const float* attr = (const float*)d_in[2];
  const float* W    = (const float*)d_in[3];
  const float* root = (const float*)d_in[4];
  const float* bias = (const float*)d_in[5];
  float* out = (float*)d_out;

  int n = in_sizes[0] / CH;   // 100000
  int E = in_sizes[2];        // 1200000

  float* S   = (float*)d_ws;
  float* A1  = S + (size_t)n * CH;
  float* deg = A1 + (size_t)n * CH;
  size_t zbytes = ((size_t)n * CH * 2 + (size_t)n) * sizeof(float);
  hipMemsetAsync(d_ws, 0, zbytes, stream);

  int sblocks = (E + 3) / 4;  // 4 edges (waves) per 256-thread block
  spline_scatter<<<sblocks, 256, 0, stream>>>(x, ei, attr, S, A1, deg, E);

  int gblocks = (n + 255) / 256;
  spline_gemm<<<gblocks, 256, 0, stream>>>(S, A1, deg, x, W, root, bias, out, n);
}